// Round 2
// baseline (1070.349 us; speedup 1.0000x reference)
//
#include <hip/hip_runtime.h>
#include <hip/hip_fp16.h>

typedef _Float16 h2v __attribute__((ext_vector_type(2)));
typedef unsigned int u32;
typedef unsigned short u16;

#define NB 256
#define NP 512
#define NH 256
#define NCOL 768

// ws layout in dwords (all fp16-pair packed weights)
#define OFF_WH 0
#define LEN_WH 98304            // 4 waves * 384 regs * 64 lanes
#define OFF_WI (OFF_WH + LEN_WH)      // 98304
#define LEN_WI 6912             // 27 regs * 256 lanes
#define OFF_W1 (OFF_WI + LEN_WI)      // 105216
#define LEN_W1 68096            // 2 * 133 * 256
#define OFF_W2 (OFF_W1 + LEN_W1)      // 173312
#define LEN_W2 65536            // 2 * 128 * 256
#define OFF_W3 (OFF_W2 + LEN_W2)      // 238848
#define LEN_W3 256              // 2 * 128
#define WS_DWORDS (OFF_W3 + LEN_W3)   // 239104 dwords = 956416 B

__device__ __forceinline__ u32 pack2(float lo, float hi) {
    h2v v; v.x = (_Float16)lo; v.y = (_Float16)hi;
    return __builtin_bit_cast(u32, v);
}

__device__ __forceinline__ float fdot2(u32 a, u32 b, float c) {
#if __has_builtin(__builtin_amdgcn_fdot2)
    return __builtin_amdgcn_fdot2(__builtin_bit_cast(h2v, a),
                                  __builtin_bit_cast(h2v, b), c, false);
#else
    h2v x = __builtin_bit_cast(h2v, a), y = __builtin_bit_cast(h2v, b);
    return c + (float)x.x * (float)y.x + (float)x.y * (float)y.y;
#endif
}

// ---------------- pack kernel: fp32 weights -> fp16-pair layouts in ws ----
__global__ __launch_bounds__(256) void pack_kernel(
    const float* __restrict__ Wi, const float* __restrict__ Whrz,
    const float* __restrict__ Whn, const float* __restrict__ W1,
    const float* __restrict__ W2, const float* __restrict__ W3,
    u32* __restrict__ ws)
{
    for (int F = blockIdx.x * 256 + threadIdx.x; F < WS_DWORDS; F += gridDim.x * 256) {
        u32 val;
        if (F < OFF_WI) {
            // Wh pack for 256-thread kernel:
            // flat = ((w*384 + i)*64 + l), i = j*32 + kk2 (j=col group, kk2=K pair)
            int l = F & 63; int t = F >> 6;        // t in [0,1536)
            int kk2 = t & 31; int t2 = t >> 5;     // t2 in [0,48)
            int j = t2 % 12; int w = t2 / 12;
            int k = 64 * w + 2 * kk2;
            int col = 64 * j + l;
            float lo, hi;
            if (col < 512) { lo = Whrz[k * 512 + col]; hi = Whrz[(k + 1) * 512 + col]; }
            else { lo = Whn[k * 256 + (col - 512)]; hi = Whn[(k + 1) * 256 + (col - 512)]; }
            val = pack2(lo, hi);
        } else if (F < OFF_W1) {
            // Wi pack: [g3*9+kk][256 lanes]; col = 256*g3 + g
            int j = F - OFF_WI; int g = j & 255; int i = j >> 8;  // i in [0,27)
            int g3 = i / 9; int kk = i % 9;
            int col = 256 * g3 + g;
            int k = 2 * kk;
            float lo = Wi[k * NCOL + col];
            float hi = (k + 1 < 17) ? Wi[(k + 1) * NCOL + col] : 0.f;
            val = pack2(lo, hi);
        } else if (F < OFF_W2) {
            int j = F - OFF_W1; int c = j / (133 * 256); int r = j % (133 * 256);
            int kk = r >> 8; int o = r & 255;
            int k = 2 * kk;
            float lo = W1[(c * 265 + k) * 256 + o];
            float hi = (k + 1 < 265) ? W1[(c * 265 + k + 1) * 256 + o] : 0.f;
            val = pack2(lo, hi);
        } else if (F < OFF_W3) {
            int j = F - OFF_W2; int c = j >> 15; int r = j & 32767;
            int kk = r >> 8; int o = r & 255;
            float lo = W2[(c * 256 + 2 * kk) * 256 + o];
            float hi = W2[(c * 256 + 2 * kk + 1) * 256 + o];
            val = pack2(lo, hi);
        } else {
            int j = F - OFF_W3; int c = j >> 7; int jj = j & 127;
            float lo = W3[c * 256 + 2 * jj];
            float hi = W3[c * 256 + 2 * jj + 1];
            val = pack2(lo, hi);
        }
        ws[F] = val;
    }
}

// ---------------- main kernel: one batch row per workgroup (256 thr) ----
// 4 waves (1/SIMD -> 512 VGPR budget). Wave w owns K-slice [64w,64w+64);
// lane l owns cols {64j + l, j=0..11}. All of Wh (384 pairs) + this thread's
// Wi columns (27 pairs) live in registers, pinned by asm.
__global__ __launch_bounds__(256, 1) void qnet_kernel(
    const float* __restrict__ particles, const float* __restrict__ pweights,
    const float* __restrict__ actions, const float* __restrict__ timev,
    const float* __restrict__ bi, const float* __restrict__ bn,
    const float* __restrict__ b1, const float* __restrict__ b2,
    const float* __restrict__ b3, const int* __restrict__ nts,
    const u32* __restrict__ ws, float* __restrict__ out)
{
    __shared__ __align__(16) u32 sX[NP * 12];        // 24576 B, x pairs, stride 12 (16B-aligned rows)
    __shared__ __align__(16) float sPart[4 * NCOL];  // 12288 B, K-slice partials
    __shared__ __align__(16) u32 sH2[NH / 2];        // 512 B, h as fp16 pairs
    __shared__ __align__(16) float sHf[NH];          // 1024 B
    __shared__ __align__(16) float sMisc[16];
    __shared__ __align__(16) u32 sHid[136];          // MLP input pairs
    __shared__ __align__(16) u16 sL1[512];
    __shared__ __align__(16) u16 sL2[512];

    const int b = blockIdx.x;
    const int tid = threadIdx.x;
    const int l = tid & 63;
    const int w = tid >> 6;    // 0..3 : K-slice

    // ---- Wh fragment: 384 fp16 pairs per lane, in registers ----
    u32 wregs[384];
    {
        const u32* gp = ws + OFF_WH + (w * 384) * 64 + l;
        #pragma unroll
        for (int i = 0; i < 384; ++i) wregs[i] = gp[i * 64];
    }
    // ---- Wi fragment: 27 pairs (3 gate-cols x 9 k-pairs) ----
    u32 wiR[27];
    #pragma unroll
    for (int i = 0; i < 27; ++i) wiR[i] = ws[OFF_WI + i * 256 + tid];
    // pin: forbid rematerialization-by-reload
    #pragma unroll
    for (int i = 0; i < 384; ++i) asm volatile("" : "+v"(wregs[i]));
    #pragma unroll
    for (int i = 0; i < 27; ++i) asm volatile("" : "+v"(wiR[i]));

    // ---- stage this row's x sequence as fp16 pairs, row stride 12 ----
    {
        const float4* pr = (const float4*)(particles + (long)b * NP * 16);
        #pragma unroll
        for (int it = 0; it < 8; ++it) {
            int f = tid + 256 * it;          // float4 index, 0..2047
            float4 v = pr[f];
            int p = f >> 2, d4 = f & 3;
            sX[p * 12 + d4 * 2]     = pack2(v.x, v.y);
            sX[p * 12 + d4 * 2 + 1] = pack2(v.z, v.w);
        }
        const float* wr = pweights + (long)b * NP;
        sX[tid * 12 + 8] = pack2(wr[tid], 0.f);
        sX[(tid + 256) * 12 + 8] = pack2(wr[tid + 256], 0.f);
    }
    if (tid < NH / 2) sH2[tid] = 0u;
    if (tid < 8) sMisc[tid] = actions[b * 8 + tid];
    if (tid == 8) sMisc[8] = timev[b] / (float)nts[0];

    const float bir = bi[tid], biz = bi[NH + tid], binn = bi[2 * NH + tid], bnn = bn[tid];
    float hreg = 0.f;
    __syncthreads();

    #pragma unroll 1
    for (int p = 0; p < NP; ++p) {
        // ---- gi = x @ Wi (independent of h; overlaps h LDS latency) ----
        float xr = bir, xz = biz, xn = binn;
        {
            uint4 xa = *(const uint4*)&sX[p * 12];
            uint4 xb = *(const uint4*)&sX[p * 12 + 4];
            u32 x8 = sX[p * 12 + 8];
            u32 xv[9] = {xa.x, xa.y, xa.z, xa.w, xb.x, xb.y, xb.z, xb.w, x8};
            #pragma unroll
            for (int kk = 0; kk < 9; ++kk) {
                xr = fdot2(wiR[kk],      xv[kk], xr);
                xz = fdot2(wiR[9 + kk],  xv[kk], xz);
                xn = fdot2(wiR[18 + kk], xv[kk], xn);
            }
        }
        // ---- main dot: K-slice(64) x 12 cols per lane ----
        float acc[12];
        #pragma unroll
        for (int j = 0; j < 12; ++j) acc[j] = 0.f;
        {
            const uint4* h4 = ((const uint4*)sH2) + w * 8;
            #pragma unroll
            for (int q = 0; q < 8; ++q) {
                uint4 hv = h4[q];
                u32 hp[4] = {hv.x, hv.y, hv.z, hv.w};
                #pragma unroll
                for (int m = 0; m < 4; ++m) {
                    #pragma unroll
                    for (int j = 0; j < 12; ++j)
                        acc[j] = fdot2(wregs[j * 32 + q * 4 + m], hp[m], acc[j]);
                }
            }
        }
        #pragma unroll
        for (int j = 0; j < 12; ++j)
            sPart[w * NCOL + j * 64 + l] = acc[j];
        __syncthreads();
        // ---- reduce + gates (all 256 threads; gate col = tid) ----
        {
            float sr = sPart[tid]            + sPart[NCOL + tid]
                     + sPart[2 * NCOL + tid] + sPart[3 * NCOL + tid];
            float sz = sPart[NH + tid]            + sPart[NCOL + NH + tid]
                     + sPart[2 * NCOL + NH + tid] + sPart[3 * NCOL + NH + tid];
            float sn = sPart[2 * NH + tid]            + sPart[NCOL + 2 * NH + tid]
                     + sPart[2 * NCOL + 2 * NH + tid] + sPart[3 * NCOL + 2 * NH + tid];
            float r = 1.f / (1.f + __expf(-(sr + xr)));
            float z = 1.f / (1.f + __expf(-(sz + xz)));
            float targ = xn + r * (sn + bnn);
            float e2 = __expf(2.f * targ);
            float n = 1.f - 2.f / (e2 + 1.f);   // tanh
            hreg = (1.f - z) * n + z * hreg;
            _Float16 hh = (_Float16)hreg;
            ((u16*)sH2)[tid] = __builtin_bit_cast(u16, hh);
        }
        __syncthreads();
    }

    // ---------------- MLP tail ----------------
    sHf[tid] = hreg;
    __syncthreads();
    if (tid < 128) sHid[tid] = pack2(sHf[2 * tid], sHf[2 * tid + 1]);
    else if (tid < 132) { int i = tid - 128; sHid[tid] = pack2(sMisc[2 * i], sMisc[2 * i + 1]); }
    else if (tid == 132) sHid[132] = pack2(sMisc[8], 0.f);
    __syncthreads();
    // L1: 2 critics x 256 outputs; thread tid does o=tid for both critics
    {
        #pragma unroll
        for (int c = 0; c < 2; ++c) {
            float acc = b1[c * 256 + tid];
            const u32* wp = ws + OFF_W1 + c * 133 * 256 + tid;
            #pragma unroll 4
            for (int kk = 0; kk < 133; ++kk) acc = fdot2(wp[kk * 256], sHid[kk], acc);
            acc = fmaxf(acc, 0.f);
            _Float16 a16 = (_Float16)acc;
            sL1[c * 256 + tid] = __builtin_bit_cast(u16, a16);
        }
    }
    __syncthreads();
    // L2
    {
        #pragma unroll
        for (int c = 0; c < 2; ++c) {
            float acc = b2[c * 256 + tid];
            const u32* wp = ws + OFF_W2 + c * 128 * 256 + tid;
            const u32* hp = (const u32*)sL1 + c * 128;
            #pragma unroll 4
            for (int kk = 0; kk < 128; ++kk) acc = fdot2(wp[kk * 256], hp[kk], acc);
            acc = fmaxf(acc, 0.f);
            _Float16 a16 = (_Float16)acc;
            sL2[c * 256 + tid] = __builtin_bit_cast(u16, a16);
        }
    }
    __syncthreads();
    // L3: 2 outputs via wave reduction
    if (tid < 128) {
        int c = tid >> 6, ll = tid & 63;
        const u32* wp = ws + OFF_W3 + c * 128;
        const u32* hp = (const u32*)sL2 + c * 128;
        float acc = fdot2(wp[ll], hp[ll], 0.f);
        acc = fdot2(wp[64 + ll], hp[64 + ll], acc);
        #pragma unroll
        for (int off = 32; off > 0; off >>= 1) acc += __shfl_down(acc, off);
        if (ll == 0) out[b * 2 + c] = acc + b3[c];
    }
}

extern "C" void kernel_launch(void* const* d_in, const int* in_sizes, int n_in,
                              void* d_out, int out_size, void* d_ws, size_t ws_size,
                              hipStream_t stream) {
    const float* particles = (const float*)d_in[0];
    const float* pweights  = (const float*)d_in[1];
    const float* actions   = (const float*)d_in[2];
    const float* timev     = (const float*)d_in[3];
    const float* Wi        = (const float*)d_in[4];
    const float* bi        = (const float*)d_in[5];
    const float* Whrz      = (const float*)d_in[6];
    const float* Whn       = (const float*)d_in[7];
    const float* bn        = (const float*)d_in[8];
    const float* W1        = (const float*)d_in[9];
    const float* b1        = (const float*)d_in[10];
    const float* W2        = (const float*)d_in[11];
    const float* b2        = (const float*)d_in[12];
    const float* W3        = (const float*)d_in[13];
    const float* b3        = (const float*)d_in[14];
    const int*   nts       = (const int*)d_in[15];
    u32* ws = (u32*)d_ws;
    float* outp = (float*)d_out;

    pack_kernel<<<WS_DWORDS / 256, 256, 0, stream>>>(Wi, Whrz, Whn, W1, W2, W3, ws);
    qnet_kernel<<<NB, 256, 0, stream>>>(particles, pweights, actions, timev,
                                        bi, bn, b1, b2, b3, nts, ws, outp);
}